// Round 2
// 944.554 us; speedup vs baseline: 1.0458x; 1.0458x over previous
//
#include <hip/hip_runtime.h>
#include <hip/hip_bf16.h>
#include <math.h>

#define HID   1024
#define IN_D  600
#define IN_DP 608      // 600 padded to multiple of 32
#define BATCH 2048
#define TSTEP 20
#define BT    (BATCH * TSTEP)   // 40960
#define G3    3072

typedef __attribute__((ext_vector_type(8))) short bf16x8;
typedef __attribute__((ext_vector_type(4))) float f32x4;

#define GLB(p) ((const __attribute__((address_space(1))) void*)(p))
#define LDS(p) ((__attribute__((address_space(3))) void*)(p))

__device__ __forceinline__ short f2bf(float f) {
    __hip_bfloat16 b = __float2bfloat16(f);
    return *(short*)&b;
}
__device__ __forceinline__ float bf2f(short s) {
    __hip_bfloat16 b = *(__hip_bfloat16*)&s;
    return __bfloat162float(b);
}

// ---------------------------------------------------------------------------
// Input projection: gx[m, n] = bf16( x_bf[m, :] . Wih[n, :] + b_ih[n] ),
// m = t*BATCH + b (x_bf pre-transposed), row-major epilogue, m97 structure.
// (unchanged — attribution isolation for the gru_step redesign)
// ---------------------------------------------------------------------------
__global__ __launch_bounds__(256) void gemm_input(const short* __restrict__ X,
                                                  const short* __restrict__ W,
                                                  const float* __restrict__ b_ih,
                                                  short* __restrict__ gx) {
    __shared__ short sA[128 * 32];
    __shared__ short sB[128 * 32];

    const int id    = blockIdx.x;
    const int xcd   = id & 7;
    const int local = id >> 3;          // 0..959
    const int nsub  = local % 3;
    const int mblk  = local / 3;        // 0..319
    const int m0 = mblk * 128;
    const int n0 = (xcd * 3 + nsub) * 128;

    const int tid  = threadIdx.x;
    const int wave = tid >> 6;
    const int lane = tid & 63;
    const int wm = (wave >> 1) * 64;
    const int wn = (wave & 1) * 64;

    const int srow = tid >> 2;
    const int scol = (tid & 3) * 8;
    const int fm = lane & 15;
    const int fq = lane >> 4;

    f32x4 acc[4][4] = {};

    for (int k0 = 0; k0 < IN_DP; k0 += 32) {
#pragma unroll
        for (int j = 0; j < 2; ++j) {
            const short* ga = X + (size_t)(m0 + j * 64 + srow) * IN_DP + k0 + scol;
            __builtin_amdgcn_global_load_lds(GLB(ga), LDS(sA + j * 2048 + wave * 512), 16, 0, 0);
            const short* gb = W + (size_t)(n0 + j * 64 + srow) * IN_DP + k0 + scol;
            __builtin_amdgcn_global_load_lds(GLB(gb), LDS(sB + j * 2048 + wave * 512), 16, 0, 0);
        }
        __syncthreads();

        bf16x8 af[4], bf[4];
#pragma unroll
        for (int mi = 0; mi < 4; ++mi)
            af[mi] = *(const bf16x8*)(sA + (wm + mi * 16 + fm) * 32 + fq * 8);
#pragma unroll
        for (int ni = 0; ni < 4; ++ni)
            bf[ni] = *(const bf16x8*)(sB + (wn + ni * 16 + fm) * 32 + fq * 8);
#pragma unroll
        for (int mi = 0; mi < 4; ++mi)
#pragma unroll
            for (int ni = 0; ni < 4; ++ni)
                acc[mi][ni] = __builtin_amdgcn_mfma_f32_16x16x32_bf16(af[mi], bf[ni], acc[mi][ni], 0, 0, 0);
        __syncthreads();
    }

#pragma unroll
    for (int ni = 0; ni < 4; ++ni) {
        int gn = n0 + wn + ni * 16 + fm;
        float bias = b_ih[gn];
#pragma unroll
        for (int mi = 0; mi < 4; ++mi) {
#pragma unroll
            for (int r = 0; r < 4; ++r) {
                int gm = m0 + wm + mi * 16 + fq * 4 + r;
                gx[(size_t)gm * G3 + gn] = f2bf(acc[mi][ni][r] + bias);
            }
        }
    }
}

// ---------------------------------------------------------------------------
// Fused recurrent step v5 (resubmit — round-1 bench failed with a
// harness-side Trio ExceptionGroup before any pytest/counter output;
// OOB/hang/swizzle audits found no kernel defect):
// 128(batch) x 64(j) x 3 gates per block, BK=64, 512 threads (8 waves =
// 2m x 4j), 256 blocks (1/CU), double-buffered.
//  - JW 32->64 halves the hb_in re-read traffic (16 panels x 4.2 MB = 67 MB)
//  - BK 32->64 halves the barrier/vmcnt-drain count (16 K-chunks)
//  - T2 XOR-swizzle (chunk ^= row&7) via pre-swizzled GLOBAL source
//    (rule #21: linear global_load_lds dest + inverse-swz source + swz read)
//    removes the 8-way ds_read_b128 bank conflict of the 64B-row layout
//  - epilogue global-read-free (sGX prefetch + hsnap from sA)
// LDS: sA 32K + sB 48K + sGX 48K = 128 KiB -> 1 block/CU (8 waves).
// ---------------------------------------------------------------------------
__global__ __launch_bounds__(512) void gru_step(const short* __restrict__ hb_in,
                                                const short* __restrict__ Wr,
                                                const short* __restrict__ gx,
                                                const float* __restrict__ b_hh,
                                                short* __restrict__ hb_out,
                                                float* __restrict__ out,
                                                int t, int last) {
    __shared__ short sA[2][128 * 64];   // 2 x 16 KB  h k-chunks (swizzled)
    __shared__ short sB[2][192 * 64];   // 2 x 24 KB  W k-chunks (swizzled)
    __shared__ short sGX[3 * 128 * 64]; // 48 KB      [gate][m][64 j] (swizzled)

    const int id   = blockIdx.x;
    const int xcd  = id & 7;
    const int rest = id >> 3;           // 0..31
    const int jsub = rest & 1;
    const int mblk = rest >> 1;         // 0..15
    const int j0 = (xcd * 2 + jsub) * 64;
    const int m0 = mblk * 128;
    const int hchunk = j0 >> 6;         // k-chunk holding h[:, j0..j0+63]

    const int tid  = threadIdx.x;
    const int wave = tid >> 6;          // 0..7
    const int lane = tid & 63;
    const int wm = (wave >> 2) * 64;    // m-group: 0 or 64
    const int jg = wave & 3;            // j-group: 16 j each
    const int fm = lane & 15;
    const int fq = lane >> 4;

    const int srow8 = lane >> 3;               // 0..7 (row within 8-row group)
    const int sxor  = ((lane & 7) ^ srow8) * 8; // inverse-swizzled col (shorts)

    const short* Wblk = Wr + (size_t)(j0 * 3) * HID;   // 192 rows, K=1024
    const short* gxt  = gx + (size_t)t * BATCH * G3;

    // ---- prefetch gx tile into sGX (6 instrs per wave, fire&forget) -------
    // instr q covers gate q>>4, rows (q&15)*8..+7, 64 j cols (swizzled source)
#pragma unroll
    for (int i = 0; i < 6; ++i) {
        int q = wave * 6 + i;           // 0..47
        int g = q >> 4;
        int row0 = (q & 15) * 8;
        const short* src = gxt + (size_t)(m0 + row0 + srow8) * G3 + g * HID + j0 + sxor;
        __builtin_amdgcn_global_load_lds(GLB(src), LDS((short*)sGX + q * 512), 16, 0, 0);
    }

    f32x4 acc[4][3] = {};    // [m-frag][gate]
    short hsnap[4][4];       // h[m-frag rows][this lane's j]

    auto stage = [&](int kc, int bsel) {
        int k0 = kc * 64;
#pragma unroll
        for (int i = 0; i < 2; ++i) {   // sA: 16 instrs over 8 waves
            int row0 = wave * 16 + i * 8;
            const short* g = hb_in + (size_t)(m0 + row0 + srow8) * HID + k0 + sxor;
            __builtin_amdgcn_global_load_lds(GLB(g), LDS(&sA[bsel][row0 * 64]), 16, 0, 0);
        }
#pragma unroll
        for (int i = 0; i < 3; ++i) {   // sB: 24 instrs over 8 waves
            int row0 = wave * 24 + i * 8;
            const short* g = Wblk + (size_t)(row0 + srow8) * HID + k0 + sxor;
            __builtin_amdgcn_global_load_lds(GLB(g), LDS(&sB[bsel][row0 * 64]), 16, 0, 0);
        }
    };

    const int jj = jg * 16 + fm;        // block-local j (0..63)

    stage(0, 0);
    for (int ic = 0; ic < 16; ++ic) {
        int cur = ic & 1;
        __syncthreads();                 // drains staging for buf cur (+ sGX on ic=0)
        if (ic + 1 < 16) stage(ic + 1, cur ^ 1);

        if (ic == hchunk) {              // snapshot h[:, j0..j0+63] from sA
#pragma unroll
            for (int mi = 0; mi < 4; ++mi)
#pragma unroll
                for (int r = 0; r < 4; ++r) {
                    int mrow = wm + mi * 16 + fq * 4 + r;
                    hsnap[mi][r] = sA[cur][mrow * 64 + (jj ^ ((mrow & 7) * 8))];
                }
        }

#pragma unroll
        for (int kk = 0; kk < 2; ++kk) {
            bf16x8 af[4], bg[3];
            const int cbase = kk * 32 + fq * 8;
            const int csw = cbase ^ ((fm & 7) * 8);   // swizzled read col
#pragma unroll
            for (int mi = 0; mi < 4; ++mi)
                af[mi] = *(const bf16x8*)(&sA[cur][(wm + mi * 16 + fm) * 64 + csw]);
#pragma unroll
            for (int g = 0; g < 3; ++g)
                bg[g] = *(const bf16x8*)(&sB[cur][(jg * 48 + g * 16 + fm) * 64 + csw]);
#pragma unroll
            for (int mi = 0; mi < 4; ++mi)
#pragma unroll
                for (int g = 0; g < 3; ++g)
                    acc[mi][g] = __builtin_amdgcn_mfma_f32_16x16x32_bf16(af[mi], bg[g], acc[mi][g], 0, 0, 0);
        }
    }

    // Epilogue: LDS/register-only inputs; global STORES only.
    const int jlane = j0 + jj;
    const float bh_r = b_hh[jlane];
    const float bh_i = b_hh[HID + jlane];
    const float bh_n = b_hh[2 * HID + jlane];

#pragma unroll
    for (int mi = 0; mi < 4; ++mi) {
#pragma unroll
        for (int r = 0; r < 4; ++r) {
            int mloc = wm + mi * 16 + fq * 4 + r;
            int gm = m0 + mloc;
            int jsw = jj ^ ((mloc & 7) * 8);          // sGX swizzled col
            float xr = bf2f(sGX[        mloc * 64 + jsw]);
            float xi = bf2f(sGX[ 8192 + mloc * 64 + jsw]);
            float xn = bf2f(sGX[16384 + mloc * 64 + jsw]);

            float rg = 1.0f / (1.0f + __expf(-(xr + acc[mi][0][r] + bh_r)));
            float ig = 1.0f / (1.0f + __expf(-(xi + acc[mi][1][r] + bh_i)));
            float ng = tanhf(xn + rg * (acc[mi][2][r] + bh_n));

            float h  = bf2f(hsnap[mi][r]);
            float hy = ng + ig * (h - ng);
            size_t idx = (size_t)gm * HID + jlane;
            hb_out[idx] = f2bf(hy);
            if (last) out[idx] = hy;
        }
    }
}

// x [b][t][600] fp32 -> x_bf [t*B + b][608] bf16 zero-padded (transpose)
__global__ __launch_bounds__(256) void cvt_x(const float* __restrict__ X, short* __restrict__ Xb) {
    int rd = blockIdx.x;             // dst row = t*BATCH + b
    int tt = rd >> 11;               // /2048
    int b  = rd & (BATCH - 1);
    const float* s = X + ((size_t)b * TSTEP + tt) * IN_D;
    short* d = Xb + (size_t)rd * IN_DP;
    for (int c = threadIdx.x; c < IN_DP; c += 256)
        d[c] = (c < IN_D) ? f2bf(s[c]) : (short)0;
}

// W_ih [3072,600] fp32 -> [3072,608] bf16 zero-padded
__global__ __launch_bounds__(256) void cvt_wih(const float* __restrict__ W, short* __restrict__ Wb) {
    int r = blockIdx.x;
    for (int c = threadIdx.x; c < IN_DP; c += 256) {
        float v = (c < IN_D) ? W[(size_t)r * IN_D + c] : 0.f;
        Wb[(size_t)r * IN_DP + c] = f2bf(v);
    }
}

// W_hh -> Wr gate-block-interleaved bf16: Wr[jb*48+g*16+ji] = Whh[g*1024+jb*16+ji]
__global__ __launch_bounds__(256) void cvt_whh(const float* __restrict__ W, short* __restrict__ Wr) {
    int n  = blockIdx.x;             // dst row 0..3071
    int jb = n / 48;
    int rem = n - jb * 48;
    int g  = rem >> 4;
    int ji = rem & 15;
    const float* s = W + (size_t)(g * HID + jb * 16 + ji) * HID;
    short* d = Wr + (size_t)n * HID;
    for (int c = threadIdx.x; c < HID; c += 256) d[c] = f2bf(s[c]);
}

extern "C" void kernel_launch(void* const* d_in, const int* in_sizes, int n_in,
                              void* d_out, int out_size, void* d_ws, size_t ws_size,
                              hipStream_t stream) {
    const float* x    = (const float*)d_in[0];  // [B, T, IN_D]
    const float* W_ih = (const float*)d_in[1];  // [3H, IN_D]
    const float* b_ih = (const float*)d_in[2];
    const float* W_hh = (const float*)d_in[3];  // [3H, HID]
    const float* b_hh = (const float*)d_in[4];
    float* out = (float*)d_out;                 // [B, HID]

    char* p = (char*)d_ws;
    short* gx     = (short*)p;  p += (size_t)BT * G3 * 2;       // 251.7 MB, [t][b][3H]
    short* x_bf   = (short*)p;  p += (size_t)BT * IN_DP * 2;    //  49.8 MB, [t][b][608]
    short* hb0    = (short*)p;  p += (size_t)BATCH * HID * 2;   //   4.2 MB
    short* hb1    = (short*)p;  p += (size_t)BATCH * HID * 2;   //   4.2 MB
    short* Wih_bf = (short*)p;  p += (size_t)G3 * IN_DP * 2;    //   3.7 MB
    short* Whh_r  = (short*)p;  p += (size_t)G3 * HID * 2;      //   6.3 MB
    // total ~320 MB

    cvt_wih<<<G3, 256, 0, stream>>>(W_ih, Wih_bf);
    cvt_whh<<<G3, 256, 0, stream>>>(W_hh, Whh_r);
    cvt_x<<<BT, 256, 0, stream>>>(x, x_bf);
    hipMemsetAsync(hb0, 0, (size_t)BATCH * HID * 2, stream);

    // One big input projection over all timesteps (M = 40960, 1D swizzled)
    gemm_input<<<7680, 256, 0, stream>>>(x_bf, Wih_bf, b_ih, gx);

    // 20 fused recurrent steps (256 blocks x 512 threads, XCD-swizzled)
    for (int t = 0; t < TSTEP; ++t) {
        const short* hin = (t & 1) ? hb1 : hb0;
        short* hout      = (t & 1) ? hb0 : hb1;
        gru_step<<<256, 512, 0, stream>>>(hin, Whh_r, gx, b_hh,
                                          hout, out, t, t == TSTEP - 1 ? 1 : 0);
    }
}

// Round 4
// 839.073 us; speedup vs baseline: 1.1773x; 1.1257x over previous
//
#include <hip/hip_runtime.h>
#include <hip/hip_bf16.h>
#include <math.h>

#define HID   1024
#define IN_D  600
#define IN_DP 608      // 600 padded to multiple of 32
#define BATCH 2048
#define TSTEP 20
#define BT    (BATCH * TSTEP)   // 40960
#define G3    3072

typedef __attribute__((ext_vector_type(8))) short bf16x8;
typedef __attribute__((ext_vector_type(4))) float f32x4;

#define GLB(p) ((const __attribute__((address_space(1))) void*)(p))
#define LDS(p) ((__attribute__((address_space(3))) void*)(p))

__device__ __forceinline__ short f2bf(float f) {
    __hip_bfloat16 b = __float2bfloat16(f);
    return *(short*)&b;
}
__device__ __forceinline__ float bf2f(short s) {
    __hip_bfloat16 b = *(__hip_bfloat16*)&s;
    return __bfloat162float(b);
}

// ---------------------------------------------------------------------------
// Input projection: gx[m, n] = bf16( x_bf[m, :] . Wih[n, :] + b_ih[n] ),
// m = t*BATCH + b (x_bf pre-transposed), row-major epilogue, m97 structure.
// (unchanged — attribution isolation for the gru_step pipeline rewrite)
// ---------------------------------------------------------------------------
__global__ __launch_bounds__(256) void gemm_input(const short* __restrict__ X,
                                                  const short* __restrict__ W,
                                                  const float* __restrict__ b_ih,
                                                  short* __restrict__ gx) {
    __shared__ short sA[128 * 32];
    __shared__ short sB[128 * 32];

    const int id    = blockIdx.x;
    const int xcd   = id & 7;
    const int local = id >> 3;          // 0..959
    const int nsub  = local % 3;
    const int mblk  = local / 3;        // 0..319
    const int m0 = mblk * 128;
    const int n0 = (xcd * 3 + nsub) * 128;

    const int tid  = threadIdx.x;
    const int wave = tid >> 6;
    const int lane = tid & 63;
    const int wm = (wave >> 1) * 64;
    const int wn = (wave & 1) * 64;

    const int srow = tid >> 2;
    const int scol = (tid & 3) * 8;
    const int fm = lane & 15;
    const int fq = lane >> 4;

    f32x4 acc[4][4] = {};

    for (int k0 = 0; k0 < IN_DP; k0 += 32) {
#pragma unroll
        for (int j = 0; j < 2; ++j) {
            const short* ga = X + (size_t)(m0 + j * 64 + srow) * IN_DP + k0 + scol;
            __builtin_amdgcn_global_load_lds(GLB(ga), LDS(sA + j * 2048 + wave * 512), 16, 0, 0);
            const short* gb = W + (size_t)(n0 + j * 64 + srow) * IN_DP + k0 + scol;
            __builtin_amdgcn_global_load_lds(GLB(gb), LDS(sB + j * 2048 + wave * 512), 16, 0, 0);
        }
        __syncthreads();

        bf16x8 af[4], bf[4];
#pragma unroll
        for (int mi = 0; mi < 4; ++mi)
            af[mi] = *(const bf16x8*)(sA + (wm + mi * 16 + fm) * 32 + fq * 8);
#pragma unroll
        for (int ni = 0; ni < 4; ++ni)
            bf[ni] = *(const bf16x8*)(sB + (wn + ni * 16 + fm) * 32 + fq * 8);
#pragma unroll
        for (int mi = 0; mi < 4; ++mi)
#pragma unroll
            for (int ni = 0; ni < 4; ++ni)
                acc[mi][ni] = __builtin_amdgcn_mfma_f32_16x16x32_bf16(af[mi], bf[ni], acc[mi][ni], 0, 0, 0);
        __syncthreads();
    }

#pragma unroll
    for (int ni = 0; ni < 4; ++ni) {
        int gn = n0 + wn + ni * 16 + fm;
        float bias = b_ih[gn];
#pragma unroll
        for (int mi = 0; mi < 4; ++mi) {
#pragma unroll
            for (int r = 0; r < 4; ++r) {
                int gm = m0 + wm + mi * 16 + fq * 4 + r;
                gx[(size_t)gm * G3 + gn] = f2bf(acc[mi][ni][r] + bias);
            }
        }
    }
}

// ---------------------------------------------------------------------------
// Fused recurrent step v7: counted-vmcnt pipeline, RACE-FIXED.
// v6 post-mortem: order was barrier -> issue -> vmcnt -> read. vmcnt is a
// PER-WAVE counter, so a wave's wait proved only its OWN rows landed; the
// fragment reads span rows staged by other waves -> cross-wave RAW race
// (reads stale previous-chunk bf16 -> absmax 0.043). The T3 recipe order is
// issue -> vmcnt(N) -> s_barrier -> read: each wave certifies its own
// contribution BEFORE the barrier; the barrier then publishes to all.
// That reorder needs NB >= D+2 = 4 staging buffers for the WAR side
// (stage(ic+2) issues in window (b[ic-1],b[ic]); buf (ic+2)%4's last reader
// ran in (b[ic-2],b[ic-1]) -> separated by b[ic-1]).
//  - 4 x 40 KB buffers = 160 KiB LDS (gfx950 per-WG max; AITER fmha ships
//    160KB-LDS kernels). Occupancy unchanged: 1 block/CU, 2 waves/SIMD.
//  - vmcnt(10) steady (15 outstanding, retire oldest 5 = chunk ic);
//    vmcnt(6) at ic=15; vmcnt(0) ONLY at epilogue (sGX drain).
//  - sGX tail-overlay now buf0 (40KB @ ic=14, last read ic=12) +
//    buf1 head (8KB @ ic=15, last read ic=13); epilogue reads LDSF[0..24576).
//  - sched_barrier(0) after each s_barrier so ds_reads can't hoist above
//    the publish point (rule #18 failure mode).
// Geometry unchanged: 128m x 64j x 3 gates, BK=64, 512 thr, 256 blocks.
// ---------------------------------------------------------------------------
__global__ __launch_bounds__(512) void gru_step(const short* __restrict__ hb_in,
                                                const short* __restrict__ Wr,
                                                const short* __restrict__ gx,
                                                const float* __restrict__ b_hh,
                                                short* __restrict__ hb_out,
                                                float* __restrict__ out,
                                                int t, int last) {
    __shared__ short LDSF[4 * 20480];   // 160 KB: buf b at b*20480 (sA@0, sB@8192)
                                        // sGX tail-overlay at [0 .. 24576)

    const int id   = blockIdx.x;
    const int xcd  = id & 7;
    const int rest = id >> 3;           // 0..31
    const int jsub = rest & 1;
    const int mblk = rest >> 1;         // 0..15
    const int j0 = (xcd * 2 + jsub) * 64;
    const int m0 = mblk * 128;
    const int hchunk = j0 >> 6;         // k-chunk holding h[:, j0..j0+63]

    const int tid  = threadIdx.x;
    const int wave = tid >> 6;          // 0..7
    const int lane = tid & 63;
    const int wm = (wave >> 2) * 64;    // m-group: 0 or 64
    const int jg = wave & 3;            // j-group: 16 j each
    const int fm = lane & 15;
    const int fq = lane >> 4;

    const int srow8 = lane >> 3;               // 0..7 (row within 8-row group)
    const int sxor  = ((lane & 7) ^ srow8) * 8; // inverse-swizzled col (shorts)

    const short* Wblk = Wr + (size_t)(j0 * 3) * HID;   // 192 rows, K=1024
    const short* gxt  = gx + (size_t)t * BATCH * G3;

    f32x4 acc[4][3] = {};    // [m-frag][gate]
    short hsnap[4][4];       // h[m-frag rows][this lane's j]

    // 5 global_load_lds per wave per chunk — UNIFORM across waves (vmcnt is
    // per-wave; the counted schedule requires symmetric issue counts).
    auto stage = [&](int kc, int bsel) {
        int k0 = kc * 64;
        short* base = LDSF + bsel * 20480;
#pragma unroll
        for (int i = 0; i < 2; ++i) {   // sA: 16 instrs over 8 waves
            int row0 = wave * 16 + i * 8;
            const short* g = hb_in + (size_t)(m0 + row0 + srow8) * HID + k0 + sxor;
            __builtin_amdgcn_global_load_lds(GLB(g), LDS(base + row0 * 64), 16, 0, 0);
        }
#pragma unroll
        for (int i = 0; i < 3; ++i) {   // sB: 24 instrs over 8 waves
            int row0 = wave * 24 + i * 8;
            const short* g = Wblk + (size_t)(row0 + srow8) * HID + k0 + sxor;
            __builtin_amdgcn_global_load_lds(GLB(g), LDS(base + 8192 + row0 * 64), 16, 0, 0);
        }
    };
    // sGX instr q (0..47): gate q>>4, rows (q&15)*8..+7, 64 swizzled j cols,
    // dest = LDSF + q*512 (buf0 + buf1 head).
    auto sgx_load = [&](int q) {
        int g = q >> 4;
        int row0 = (q & 15) * 8;
        const short* src = gxt + (size_t)(m0 + row0 + srow8) * G3 + g * HID + j0 + sxor;
        __builtin_amdgcn_global_load_lds(GLB(src), LDS(LDSF + q * 512), 16, 0, 0);
    };

    const int jj = jg * 16 + fm;        // block-local j (0..63)

    stage(0, 0);
    stage(1, 1);

#pragma unroll
    for (int ic = 0; ic < 16; ++ic) {
        // ---- issue (writes a buffer whose readers finished >=2 barriers ago)
        if (ic < 14) {
            stage(ic + 2, (ic + 2) & 3);          // 5 loads/wave
        } else if (ic == 14) {
#pragma unroll
            for (int i = 0; i < 5; ++i) sgx_load(wave * 5 + i);   // 40KB -> buf0
        } else {
            sgx_load(40 + wave);                  // 8KB -> buf1 head, 1/wave
        }
        // ---- counted wait on OWN chunk-ic loads, THEN publish via barrier.
        // ic<=14: outstanding 15 (ic,ic+1,next) -> vmcnt(10) retires chunk ic.
        // ic==15: outstanding 11 (chunk15=5, sgxA=5, sgxB=1) -> vmcnt(6).
        if (ic < 15) asm volatile("s_waitcnt vmcnt(10)" : : : "memory");
        else         asm volatile("s_waitcnt vmcnt(6)"  : : : "memory");
        __builtin_amdgcn_s_barrier();
        __builtin_amdgcn_sched_barrier(0);        // no reads hoist above publish

        short* buf = LDSF + (ic & 3) * 20480;

        if (ic == hchunk) {              // snapshot h[:, j0..j0+63] from sA
#pragma unroll
            for (int mi = 0; mi < 4; ++mi)
#pragma unroll
                for (int r = 0; r < 4; ++r) {
                    int mrow = wm + mi * 16 + fq * 4 + r;
                    hsnap[mi][r] = buf[mrow * 64 + (jj ^ ((mrow & 7) * 8))];
                }
        }

#pragma unroll
        for (int kk = 0; kk < 2; ++kk) {
            bf16x8 af[4], bg[3];
            const int cbase = kk * 32 + fq * 8;
            const int csw = cbase ^ ((fm & 7) * 8);   // swizzled read col
#pragma unroll
            for (int mi = 0; mi < 4; ++mi)
                af[mi] = *(const bf16x8*)(&buf[(wm + mi * 16 + fm) * 64 + csw]);
#pragma unroll
            for (int g = 0; g < 3; ++g)
                bg[g] = *(const bf16x8*)(&buf[8192 + (jg * 48 + g * 16 + fm) * 64 + csw]);
            __builtin_amdgcn_s_setprio(1);
#pragma unroll
            for (int mi = 0; mi < 4; ++mi)
#pragma unroll
                for (int g = 0; g < 3; ++g)
                    acc[mi][g] = __builtin_amdgcn_mfma_f32_16x16x32_bf16(af[mi], bg[g], acc[mi][g], 0, 0, 0);
            __builtin_amdgcn_s_setprio(0);
        }
    }

    // Drain sGX (only remaining outstanding loads), publish, then the
    // epilogue is LDS/register-only inputs; global STORES only.
    asm volatile("s_waitcnt vmcnt(0)" : : : "memory");
    __builtin_amdgcn_s_barrier();
    __builtin_amdgcn_sched_barrier(0);

    const short* sGX = LDSF;            // [0 .. 24576) shorts
    const int jlane = j0 + jj;
    const float bh_r = b_hh[jlane];
    const float bh_i = b_hh[HID + jlane];
    const float bh_n = b_hh[2 * HID + jlane];

#pragma unroll
    for (int mi = 0; mi < 4; ++mi) {
#pragma unroll
        for (int r = 0; r < 4; ++r) {
            int mloc = wm + mi * 16 + fq * 4 + r;
            int gm = m0 + mloc;
            int jsw = jj ^ ((mloc & 7) * 8);          // sGX swizzled col
            float xr = bf2f(sGX[        mloc * 64 + jsw]);
            float xi = bf2f(sGX[ 8192 + mloc * 64 + jsw]);
            float xn = bf2f(sGX[16384 + mloc * 64 + jsw]);

            float rg = 1.0f / (1.0f + __expf(-(xr + acc[mi][0][r] + bh_r)));
            float ig = 1.0f / (1.0f + __expf(-(xi + acc[mi][1][r] + bh_i)));
            float ng = tanhf(xn + rg * (acc[mi][2][r] + bh_n));

            float h  = bf2f(hsnap[mi][r]);
            float hy = ng + ig * (h - ng);
            size_t idx = (size_t)gm * HID + jlane;
            hb_out[idx] = f2bf(hy);
            if (last) out[idx] = hy;
        }
    }
}

// x [b][t][600] fp32 -> x_bf [t*B + b][608] bf16 zero-padded (transpose)
__global__ __launch_bounds__(256) void cvt_x(const float* __restrict__ X, short* __restrict__ Xb) {
    int rd = blockIdx.x;             // dst row = t*BATCH + b
    int tt = rd >> 11;               // /2048
    int b  = rd & (BATCH - 1);
    const float* s = X + ((size_t)b * TSTEP + tt) * IN_D;
    short* d = Xb + (size_t)rd * IN_DP;
    for (int c = threadIdx.x; c < IN_DP; c += 256)
        d[c] = (c < IN_D) ? f2bf(s[c]) : (short)0;
}

// W_ih [3072,600] fp32 -> [3072,608] bf16 zero-padded
__global__ __launch_bounds__(256) void cvt_wih(const float* __restrict__ W, short* __restrict__ Wb) {
    int r = blockIdx.x;
    for (int c = threadIdx.x; c < IN_DP; c += 256) {
        float v = (c < IN_D) ? W[(size_t)r * IN_D + c] : 0.f;
        Wb[(size_t)r * IN_DP + c] = f2bf(v);
    }
}

// W_hh -> Wr gate-block-interleaved bf16: Wr[jb*48+g*16+ji] = Whh[g*1024+jb*16+ji]
__global__ __launch_bounds__(256) void cvt_whh(const float* __restrict__ W, short* __restrict__ Wr) {
    int n  = blockIdx.x;             // dst row 0..3071
    int jb = n / 48;
    int rem = n - jb * 48;
    int g  = rem >> 4;
    int ji = rem & 15;
    const float* s = W + (size_t)(g * HID + jb * 16 + ji) * HID;
    short* d = Wr + (size_t)n * HID;
    for (int c = threadIdx.x; c < HID; c += 256) d[c] = f2bf(s[c]);
}

extern "C" void kernel_launch(void* const* d_in, const int* in_sizes, int n_in,
                              void* d_out, int out_size, void* d_ws, size_t ws_size,
                              hipStream_t stream) {
    const float* x    = (const float*)d_in[0];  // [B, T, IN_D]
    const float* W_ih = (const float*)d_in[1];  // [3H, IN_D]
    const float* b_ih = (const float*)d_in[2];
    const float* W_hh = (const float*)d_in[3];  // [3H, HID]
    const float* b_hh = (const float*)d_in[4];
    float* out = (float*)d_out;                 // [B, HID]

    char* p = (char*)d_ws;
    short* gx     = (short*)p;  p += (size_t)BT * G3 * 2;       // 251.7 MB, [t][b][3H]
    short* x_bf   = (short*)p;  p += (size_t)BT * IN_DP * 2;    //  49.8 MB, [t][b][608]
    short* hb0    = (short*)p;  p += (size_t)BATCH * HID * 2;   //   4.2 MB
    short* hb1    = (short*)p;  p += (size_t)BATCH * HID * 2;   //   4.2 MB
    short* Wih_bf = (short*)p;  p += (size_t)G3 * IN_DP * 2;    //   3.7 MB
    short* Whh_r  = (short*)p;  p += (size_t)G3 * HID * 2;      //   6.3 MB
    // total ~320 MB

    cvt_wih<<<G3, 256, 0, stream>>>(W_ih, Wih_bf);
    cvt_whh<<<G3, 256, 0, stream>>>(W_hh, Whh_r);
    cvt_x<<<BT, 256, 0, stream>>>(x, x_bf);
    hipMemsetAsync(hb0, 0, (size_t)BATCH * HID * 2, stream);

    // One big input projection over all timesteps (M = 40960, 1D swizzled)
    gemm_input<<<7680, 256, 0, stream>>>(x_bf, Wih_bf, b_ih, gx);

    // 20 fused recurrent steps (256 blocks x 512 threads, XCD-swizzled)
    for (int t = 0; t < TSTEP; ++t) {
        const short* hin = (t & 1) ? hb1 : hb0;
        short* hout      = (t & 1) ? hb0 : hb1;
        gru_step<<<256, 512, 0, stream>>>(hin, Whh_r, gx, b_hh,
                                          hout, out, t, t == TSTEP - 1 ? 1 : 0);
    }
}